// Round 1
// baseline (324.046 us; speedup 1.0000x reference)
//
#include <hip/hip_runtime.h>

#define NWIN 640
#define ZHW  144
#define DIM  192
#define HEADS 6
#define DH   32
#define TW   64
#define RSCALE 0.17677669529663689f

typedef float f32x4 __attribute__((ext_vector_type(4)));
typedef __bf16 bf16x8 __attribute__((ext_vector_type(8)));

__device__ __forceinline__ unsigned short f2b(float f) {
  unsigned u = __float_as_uint(f);
  u += 0x7fffu + ((u >> 16) & 1u);
  return (unsigned short)(u >> 16);
}
__device__ __forceinline__ float b2f(unsigned v) { return __uint_as_float(v << 16); }

// Load an A/B fragment for mfma_f32_16x16x32_bf16 from row-major LDS:
// lane needs elements k0..k0+3 and k0+16..k0+19 of its row (k0 = 4*(lane>>4)).
__device__ __forceinline__ bf16x8 ld_frag(const unsigned short* p) {
  uint2 lo = *(const uint2*)(p);
  uint2 hi = *(const uint2*)(p + 16);
  uint4 u; u.x = lo.x; u.y = lo.y; u.z = hi.x; u.w = hi.y;
  return __builtin_bit_cast(bf16x8, u);
}
#define MFMA16(a, b, c) __builtin_amdgcn_mfma_f32_16x16x32_bf16((a), (b), (c), 0, 0, 0)

// ---- attn kernel LDS layout (bytes) ----
#define XS_LD 196
#define WT_LD 196
#define QS_LD 36
#define VT_LD 164
#define BS_LD 148
#define XS_OFF 0        // xs [144][196] bf16 = 56448
#define WT_OFF 56448    // wt [32][196]  bf16 = 12544
#define QS_OFF 68992    // qs [144][36]  bf16 = 10368
#define KS_OFF 79360    // ks [144][36]  bf16 = 10368
#define VT_OFF 89728    // vt [32][164]  bf16 = 10496 (cols 144..163 zero pad)
#define BS_OFF 100224   // bs [144][148] bf16 = 42624
#define MS_OFF 142848   // ms [144][144] u8   = 20736
#define SMEM_SZ 163584  // <= 163840

__global__ __launch_bounds__(576) void attn_kernel(
    const float* __restrict__ x, const float* __restrict__ mask,
    const float* __restrict__ b1, const unsigned short* __restrict__ w1t,
    const unsigned short* __restrict__ biasm, unsigned short* __restrict__ xbuf)
{
  __shared__ __align__(16) unsigned char smem[SMEM_SZ];
  unsigned short* xs = (unsigned short*)(smem + XS_OFF);
  unsigned short* wt = (unsigned short*)(smem + WT_OFF);
  unsigned short* qs = (unsigned short*)(smem + QS_OFF);
  unsigned short* kq = (unsigned short*)(smem + KS_OFF);
  unsigned short* vt = (unsigned short*)(smem + VT_OFF);
  unsigned short* bs = (unsigned short*)(smem + BS_OFF);
  unsigned char*  ms = (unsigned char*)(smem + MS_OFF);

  const int tid  = threadIdx.x;
  const int wv   = tid >> 6;         // wave 0..8, owns token/q strip [16wv,16wv+16)
  const int lane = tid & 63;
  const int l15  = lane & 15;
  const int g    = lane >> 4;
  const int win  = blockIdx.x;
  const int wtype = win & (TW - 1);

  // stage x -> xs (bf16)
  {
    const float4* src = (const float4*)(x + (size_t)win * ZHW * DIM);
    #pragma unroll 1
    for (int i = tid; i < ZHW * DIM / 4; i += 576) {
      float4 v = src[i];
      int e = i * 4, r = e / DIM, c = e % DIM;
      uint2 pk;
      pk.x = (unsigned)f2b(v.x) | ((unsigned)f2b(v.y) << 16);
      pk.y = (unsigned)f2b(v.z) | ((unsigned)f2b(v.w) << 16);
      *(uint2*)(xs + r * XS_LD + c) = pk;
    }
  }
  // stage mask -> ms (1 byte per element: 0 or 1, 1 means -100)
  {
    const float4* src = (const float4*)(mask + (size_t)win * ZHW * ZHW);
    #pragma unroll 1
    for (int i = tid; i < ZHW * ZHW / 4; i += 576) {
      float4 v = src[i];
      unsigned b = (v.x != 0.f ? 1u : 0u) | ((v.y != 0.f ? 1u : 0u) << 8) |
                   ((v.z != 0.f ? 1u : 0u) << 16) | ((v.w != 0.f ? 1u : 0u) << 24);
      *(unsigned*)(ms + i * 4) = b;
    }
  }
  // zero vt pad columns [144,164) once (PV kstep 4 reads kk 144..159 as zeros)
  for (int i = tid; i < 32 * (VT_LD - ZHW); i += 576) {
    int r = i / (VT_LD - ZHW), c = ZHW + i % (VT_LD - ZHW);
    vt[r * VT_LD + c] = 0;
  }

  f32x4 st[9];
  #pragma unroll 1
  for (int h = 0; h < HEADS; ++h) {
    __syncthreads();  // prior-head LDS reads done (h=0: initial staging published below)
    // stage bias slice [wtype][h] -> bs
    {
      const uint2* src = (const uint2*)(biasm + (size_t)(wtype * HEADS + h) * ZHW * ZHW);
      #pragma unroll 1
      for (int i = tid; i < ZHW * ZHW / 4; i += 576) {
        int e = i * 4, r = e / ZHW, c = e % ZHW;
        *(uint2*)(bs + r * BS_LD + c) = src[i];
      }
    }
    // ---- QKV projection for this head: 3 GEMMs (144x192)@(192x32) ----
    #pragma unroll 1
    for (int mat = 0; mat < 3; ++mat) {
      {
        const uint2* src = (const uint2*)(w1t + (size_t)(mat * DIM + h * DH) * DIM);
        #pragma unroll 1
        for (int i = tid; i < DH * DIM / 4; i += 576) {
          int e = i * 4, r = e / DIM, c = e % DIM;
          *(uint2*)(wt + r * WT_LD + c) = src[i];
        }
      }
      __syncthreads();  // wt ready (and for h=0/mat=0: xs/ms/bs ready)
      f32x4 acc[2];
      {
        int cb = mat * DIM + h * DH;
        #pragma unroll
        for (int nt = 0; nt < 2; ++nt) {
          float bv = b1[cb + nt * 16 + l15];
          acc[nt][0] = bv; acc[nt][1] = bv; acc[nt][2] = bv; acc[nt][3] = bv;
        }
      }
      const unsigned short* arow = xs + (wv * 16 + l15) * XS_LD + 4 * g;
      const unsigned short* br0  = wt + l15 * WT_LD + 4 * g;
      const unsigned short* br1  = wt + (16 + l15) * WT_LD + 4 * g;
      #pragma unroll
      for (int kk = 0; kk < 6; ++kk) {
        bf16x8 a = ld_frag(arow + kk * 32);
        acc[0] = MFMA16(a, ld_frag(br0 + kk * 32), acc[0]);
        acc[1] = MFMA16(a, ld_frag(br1 + kk * 32), acc[1]);
      }
      // D layout: row = 4g+j (token_local), col = l15 (n)
      if (mat < 2) {
        unsigned short* dst = (mat == 0) ? qs : kq;
        #pragma unroll
        for (int nt = 0; nt < 2; ++nt)
          #pragma unroll
          for (int j = 0; j < 4; ++j)
            dst[(wv * 16 + 4 * g + j) * QS_LD + nt * 16 + l15] = f2b(acc[nt][j]);
      } else {  // V stored transposed: vt[d][token]
        #pragma unroll
        for (int nt = 0; nt < 2; ++nt) {
          uint2 pk;
          pk.x = (unsigned)f2b(acc[nt][0]) | ((unsigned)f2b(acc[nt][1]) << 16);
          pk.y = (unsigned)f2b(acc[nt][2]) | ((unsigned)f2b(acc[nt][3]) << 16);
          *(uint2*)(vt + (nt * 16 + l15) * VT_LD + wv * 16 + 4 * g) = pk;
        }
      }
      __syncthreads();  // publish q/k/v stores; protect wt before restage
    }
    // ---- S^T = K·Q^T : wave owns q columns [16wv,16wv+16) ----
    const int q = wv * 16 + l15;
    bf16x8 bq = ld_frag(qs + q * QS_LD + 4 * g);
    #pragma unroll
    for (int kst = 0; kst < 9; ++kst) {
      bf16x8 ak = ld_frag(kq + (kst * 16 + l15) * QS_LD + 4 * g);
      f32x4 z; z[0] = 0.f; z[1] = 0.f; z[2] = 0.f; z[3] = 0.f;
      st[kst] = MFMA16(ak, bq, z);  // lane: St[kk=16kst+4g+j][q]
    }
    // ---- softmax over kk (per lane: 36 vals; reduce with lanes l15+16g) ----
    float mx = -1e30f;
    #pragma unroll
    for (int kst = 0; kst < 9; ++kst) {
      int kk0 = kst * 16 + 4 * g;
      uint2 bb = *(const uint2*)(bs + q * BS_LD + kk0);
      unsigned mm = *(const unsigned*)(ms + q * ZHW + kk0);
      f32x4 s = st[kst];
      s[0] = s[0] * RSCALE + b2f(bb.x & 0xffffu) + ((mm & 0xffu)       ? -100.f : 0.f);
      s[1] = s[1] * RSCALE + b2f(bb.x >> 16)     + ((mm & 0xff00u)     ? -100.f : 0.f);
      s[2] = s[2] * RSCALE + b2f(bb.y & 0xffffu) + ((mm & 0xff0000u)   ? -100.f : 0.f);
      s[3] = s[3] * RSCALE + b2f(bb.y >> 16)     + ((mm & 0xff000000u) ? -100.f : 0.f);
      st[kst] = s;
      mx = fmaxf(mx, fmaxf(fmaxf(s[0], s[1]), fmaxf(s[2], s[3])));
    }
    mx = fmaxf(mx, __shfl_xor(mx, 16));
    mx = fmaxf(mx, __shfl_xor(mx, 32));
    float sum = 0.f;
    #pragma unroll
    for (int kst = 0; kst < 9; ++kst) {
      f32x4 s = st[kst];
      s[0] = __expf(s[0] - mx); s[1] = __expf(s[1] - mx);
      s[2] = __expf(s[2] - mx); s[3] = __expf(s[3] - mx);
      st[kst] = s;
      sum += s[0] + s[1] + s[2] + s[3];
    }
    sum += __shfl_xor(sum, 16);
    sum += __shfl_xor(sum, 32);
    float inv = 1.f / sum;
    // P registers already match the PV B-fragment layout (no cross-lane moves)
    bf16x8 pb[5];
    #pragma unroll
    for (int s5 = 0; s5 < 5; ++s5) {
      unsigned short e[8];
      #pragma unroll
      for (int j = 0; j < 4; ++j) e[j] = f2b(st[2 * s5][j] * inv);
      if (s5 < 4) {
        #pragma unroll
        for (int j = 0; j < 4; ++j) e[4 + j] = f2b(st[2 * s5 + 1][j] * inv);
      } else {
        e[4] = 0; e[5] = 0; e[6] = 0; e[7] = 0;  // kk 144..159 pad
      }
      uint4 u;
      u.x = (unsigned)e[0] | ((unsigned)e[1] << 16);
      u.y = (unsigned)e[2] | ((unsigned)e[3] << 16);
      u.z = (unsigned)e[4] | ((unsigned)e[5] << 16);
      u.w = (unsigned)e[6] | ((unsigned)e[7] << 16);
      pb[s5] = __builtin_bit_cast(bf16x8, u);
    }
    // ---- O^T = V^T · P^T, then store into the swapaxes-scrambled layout:
    // S[h][win][q][d] -> xbuf[24*(h*640+win) + q/6][(q%6)*32 + d]
    int m = h * NWIN + win;
    unsigned short* xrow = xbuf + (size_t)(24 * m + q / 6) * DIM + (q % 6) * DH + 4 * g;
    #pragma unroll
    for (int dt = 0; dt < 2; ++dt) {
      const unsigned short* vrow = vt + (dt * 16 + l15) * VT_LD + 4 * g;
      f32x4 ot; ot[0] = 0.f; ot[1] = 0.f; ot[2] = 0.f; ot[3] = 0.f;
      #pragma unroll
      for (int s5 = 0; s5 < 5; ++s5)
        ot = MFMA16(ld_frag(vrow + s5 * 32), pb[s5], ot);
      uint2 pk;
      pk.x = (unsigned)f2b(ot[0]) | ((unsigned)f2b(ot[1]) << 16);
      pk.y = (unsigned)f2b(ot[2]) | ((unsigned)f2b(ot[3]) << 16);
      *(uint2*)(xrow + dt * 16) = pk;
    }
  }
}

// ---- out projection: out = xbuf(92160x192 bf16) @ w2 + b2 (fp32) ----
__global__ __launch_bounds__(512) void proj_kernel(
    const unsigned short* __restrict__ xbuf, const unsigned short* __restrict__ w2t,
    const float* __restrict__ b2, float* __restrict__ out)
{
  __shared__ __align__(16) unsigned char smem[125440];
  unsigned short* xb = (unsigned short*)smem;            // [128][196]
  unsigned short* wb = (unsigned short*)(smem + 50176);  // [192][196]
  const int tid = threadIdx.x, wv = tid >> 6, lane = tid & 63;
  const int l15 = lane & 15, g = lane >> 4;
  const int r0 = blockIdx.x * 128;
  {
    const uint2* src = (const uint2*)(xbuf + (size_t)r0 * DIM);
    #pragma unroll 1
    for (int i = tid; i < 128 * DIM / 4; i += 512) {
      int e = i * 4, r = e / DIM, c = e % DIM;
      *(uint2*)(xb + r * 196 + c) = src[i];
    }
    const uint2* wsrc = (const uint2*)w2t;
    #pragma unroll 1
    for (int i = tid; i < DIM * DIM / 4; i += 512) {
      int e = i * 4, r = e / DIM, c = e % DIM;
      *(uint2*)(wb + r * 196 + c) = wsrc[i];
    }
  }
  __syncthreads();
  bf16x8 a[6];
  const unsigned short* arow = xb + (wv * 16 + l15) * 196 + 4 * g;
  #pragma unroll
  for (int kk = 0; kk < 6; ++kk) a[kk] = ld_frag(arow + kk * 32);
  #pragma unroll 1
  for (int nt = 0; nt < 12; ++nt) {
    float bv = b2[nt * 16 + l15];
    f32x4 acc; acc[0] = bv; acc[1] = bv; acc[2] = bv; acc[3] = bv;
    const unsigned short* brow = wb + (nt * 16 + l15) * 196 + 4 * g;
    #pragma unroll
    for (int kk = 0; kk < 6; ++kk) acc = MFMA16(a[kk], ld_frag(brow + kk * 32), acc);
    float* orow = out + (size_t)(r0 + wv * 16) * DIM + nt * 16 + l15;
    #pragma unroll
    for (int j = 0; j < 4; ++j) orow[(4 * g + j) * DIM] = acc[j];
  }
}

// ---- prep: transpose weights to bf16 n-major (B-fragment friendly) ----
__global__ void prep_w(const float* __restrict__ w1, const float* __restrict__ w2,
                       unsigned short* __restrict__ w1t, unsigned short* __restrict__ w2t)
{
  int i = blockIdx.x * 256 + threadIdx.x;
  if (i < 576 * 192) { int n = i / 192, k = i % 192; w1t[i] = f2b(w1[k * 576 + n]); }
  if (i < 192 * 192) { int n = i / 192, k = i % 192; w2t[i] = f2b(w2[k * 192 + n]); }
}

// ---- prep: materialize bias[wtype*6+h][q*144+kk] bf16 via LDS transpose ----
__global__ void prep_bias(const float* __restrict__ table, const int* __restrict__ pidx,
                          unsigned short* __restrict__ biasm)
{
  __shared__ float ld[64 * 385];
  const int tid = threadIdx.x;
  const int p0 = blockIdx.x * 64;
  #pragma unroll 1
  for (int i = tid; i < 64 * 384; i += 256) {
    int pl = i / 384, wh = i % 384;
    ld[pl * 385 + wh] = table[(size_t)pidx[p0 + pl] * 384 + wh];  // coalesced 384-f32 rows
  }
  __syncthreads();
  #pragma unroll 1
  for (int i = tid; i < 384 * 64; i += 256) {
    int wh = i / 64, pl = i % 64;
    biasm[(size_t)wh * (ZHW * ZHW) + p0 + pl] = f2b(ld[pl * 385 + wh]);  // coalesced writes
  }
}

extern "C" void kernel_launch(void* const* d_in, const int* in_sizes, int n_in,
                              void* d_out, int out_size, void* d_ws, size_t ws_size,
                              hipStream_t stream)
{
  const float* x     = (const float*)d_in[0];
  const float* mask  = (const float*)d_in[1];
  const float* w1    = (const float*)d_in[2];
  const float* b1    = (const float*)d_in[3];
  const float* w2    = (const float*)d_in[4];
  const float* b2    = (const float*)d_in[5];
  const float* table = (const float*)d_in[6];
  const int*   pidx  = (const int*)d_in[7];
  float* out = (float*)d_out;
  unsigned char* ws = (unsigned char*)d_ws;
  // ws layout: w1t 221184 | w2t 73728 | biasm 15925248 | xbuf 35389440  (~49.2 MiB)
  unsigned short* w1t   = (unsigned short*)(ws);
  unsigned short* w2t   = (unsigned short*)(ws + 221184);
  unsigned short* biasm = (unsigned short*)(ws + 294912);
  unsigned short* xbuf  = (unsigned short*)(ws + 16220160);

  prep_w   <<<dim3(432), dim3(256), 0, stream>>>(w1, w2, w1t, w2t);
  prep_bias<<<dim3(324), dim3(256), 0, stream>>>(table, pidx, biasm);
  attn_kernel<<<dim3(640), dim3(576), 0, stream>>>(x, mask, b1, w1t, biasm, xbuf);
  proj_kernel<<<dim3(720), dim3(512), 0, stream>>>(xbuf, w2t, b2, out);
}